// Round 1
// baseline (6021.670 us; speedup 1.0000x reference)
//
#include <hip/hip_runtime.h>
#include <hip/hip_bf16.h>

typedef unsigned short u16;
typedef __attribute__((ext_vector_type(8))) short short8;
typedef __attribute__((ext_vector_type(4))) float f32x4;

__device__ __forceinline__ u16 f2bf(float f) {
  unsigned u = __float_as_uint(f);
  u += 0x7FFFu + ((u >> 16) & 1u);
  return (u16)(u >> 16);
}
__device__ __forceinline__ float bf2f(u16 b) {
  return __uint_as_float(((unsigned)b) << 16);
}

// f32 -> bf16 convert (4 elems/thread)
__global__ void cvt_kernel(const float* __restrict__ in, u16* __restrict__ out, int n) {
  int i = (blockIdx.x * blockDim.x + threadIdx.x) * 4;
  if (i < n) {
    f32x4 v = *(const f32x4*)(in + i);
    out[i + 0] = f2bf(v[0]);
    out[i + 1] = f2bf(v[1]);
    out[i + 2] = f2bf(v[2]);
    out[i + 3] = f2bf(v[3]);
  }
}

// ---------------------------------------------------------------------------
// Tiled bf16 MFMA GEMM:  C[M][N] = A[M][K] * B[N][K]^T + bias[N]
// BM=BN=128, BK=128, block=512 (8 waves), static LDS 64KB, XOR-swizzled chunks.
// ---------------------------------------------------------------------------
template <bool A_F32, bool OUT_F32>
__global__ __launch_bounds__(512, 1) void gemm_kernel(
    const void* __restrict__ Ag, const u16* __restrict__ Bg,
    const float* __restrict__ bias, void* __restrict__ Cg,
    int M, int N, int K) {
  __shared__ __align__(16) u16 As[128 * 128];
  __shared__ __align__(16) u16 Bs[128 * 128];
  const int tid = threadIdx.x;
  const int lane = tid & 63, wave = tid >> 6;
  const int wm = wave & 1, wn = wave >> 1;  // wm: 64-row half, wn: 32-col quarter
  const int m0 = blockIdx.x * 128, n0 = blockIdx.y * 128;

  f32x4 acc[4][2];
#pragma unroll
  for (int i = 0; i < 4; ++i) {
    acc[i][0] = (f32x4){0.f, 0.f, 0.f, 0.f};
    acc[i][1] = (f32x4){0.f, 0.f, 0.f, 0.f};
  }

  const int nk = K >> 7;
  for (int ks = 0; ks < nk; ++ks) {
    // stage A: 128 rows x 16 chunks of 8 bf16 (16B), chunk index XOR-swizzled
    for (int i = tid; i < 128 * 16; i += 512) {
      int r = i >> 4, c = i & 15;
      int sw = c ^ (r & 7);
      short8 v;
      if (A_F32) {
        const float* ap = (const float*)Ag + (size_t)(m0 + r) * K + ks * 128 + c * 8;
#pragma unroll
        for (int e = 0; e < 8; ++e) v[e] = (short)f2bf(ap[e]);
      } else {
        v = *(const short8*)((const u16*)Ag + (size_t)(m0 + r) * K + ks * 128 + c * 8);
      }
      *(short8*)(As + (r * 16 + sw) * 8) = v;
    }
    // stage B
    for (int i = tid; i < 128 * 16; i += 512) {
      int r = i >> 4, c = i & 15;
      int sw = c ^ (r & 7);
      *(short8*)(Bs + (r * 16 + sw) * 8) =
          *(const short8*)(Bg + (size_t)(n0 + r) * K + ks * 128 + c * 8);
    }
    __syncthreads();
#pragma unroll
    for (int kb = 0; kb < 4; ++kb) {
      const int cq = kb * 4 + (lane >> 4);
      short8 bfr[2];
#pragma unroll
      for (int j = 0; j < 2; ++j) {
        int rr = wn * 32 + j * 16 + (lane & 15);
        bfr[j] = *(const short8*)(Bs + (rr * 16 + (cq ^ (rr & 7))) * 8);
      }
#pragma unroll
      for (int i2 = 0; i2 < 4; ++i2) {
        int rr = wm * 64 + i2 * 16 + (lane & 15);
        short8 af = *(const short8*)(As + (rr * 16 + (cq ^ (rr & 7))) * 8);
        acc[i2][0] = __builtin_amdgcn_mfma_f32_16x16x32_bf16(af, bfr[0], acc[i2][0], 0, 0, 0);
        acc[i2][1] = __builtin_amdgcn_mfma_f32_16x16x32_bf16(af, bfr[1], acc[i2][1], 0, 0, 0);
      }
    }
    __syncthreads();
  }
  // epilogue: D[row=(lane>>4)*4+r][col=lane&15] per 16x16 tile (guide-verified)
#pragma unroll
  for (int i2 = 0; i2 < 4; ++i2) {
#pragma unroll
    for (int j = 0; j < 2; ++j) {
      int ncol = n0 + wn * 32 + j * 16 + (lane & 15);
      float bv = bias[ncol];
#pragma unroll
      for (int r2 = 0; r2 < 4; ++r2) {
        int mrow = m0 + wm * 64 + i2 * 16 + ((lane >> 4) << 2) + r2;
        float v = acc[i2][j][r2] + bv;
        if (OUT_F32)
          ((float*)Cg)[(size_t)mrow * N + ncol] = v;
        else
          ((u16*)Cg)[(size_t)mrow * N + ncol] = f2bf(v);
      }
    }
  }
}

// ---------------------------------------------------------------------------
// Persistent GRU recurrence. 32 WGs x 512 threads; WG k owns h-columns
// j0..j0+15 (48 gate rows of w_hh: r/z/n for those j). Weights LDS-resident
// (bf16 hi in LDS frag order, bf16 lo in registers of the 6 GEMM waves).
// Per step: waves 0-5 do the 32x48 = h(t-1) @ Wslice^T MFMA GEMM (A from
// global hs bf16), waves 6-7 stage wx_t slice; then gates + h_new; then
// device-scope flag barrier (monotonic per-WG step flags).
// ---------------------------------------------------------------------------
#define T_STEPS 1024

__global__ __launch_bounds__(512, 1) void gru_kernel(
    const float* __restrict__ w_hh, const float* __restrict__ b_hh,
    const u16* __restrict__ wx, u16* __restrict__ hs,
    unsigned* __restrict__ flags) {
  __shared__ __align__(16) u16 whi[3 * 16 * 64 * 8];  // 48KB: W hi frags
  __shared__ float whb[32 * 48];                      // 6KB: wh = h@W^T
  __shared__ float wxb[32 * 48];                      // 6KB: wx_t slice
  __shared__ float hold[512];                         // f32 h state (our 16 cols x 32 seq)
  __shared__ float bsl[48];                           // b_hh slice

  const int tid = threadIdx.x;
  const int wg = blockIdx.x;
  const int j0 = wg * 16;
  const int lane = tid & 63, wave = tid >> 6;

  // ---- init: W hi -> LDS frag order; b_hh slice; h state = 0
  for (int i = tid; i < 48 * 512; i += 512) {
    int rr = i >> 9, k = i & 511;
    int ng = rr >> 4, jj = rr & 15;
    float w = w_hh[(size_t)(ng * 512 + j0 + jj) * 512 + k];
    int idx = (((ng * 16 + (k >> 5)) * 64) + ((k & 31) >> 3) * 16 + jj) * 8 + (k & 7);
    whi[idx] = f2bf(w);
  }
  if (tid < 48) bsl[tid] = b_hh[(tid >> 4) * 512 + j0 + (tid & 15)];
  hold[tid] = 0.f;

  const int mt = wave & 1, ng = wave >> 1;  // GEMM role for waves 0..5
  short8 wlo[16];
  if (wave < 6) {
    const int grow = ng * 512 + j0 + (lane & 15);
    const int kofs = (lane >> 4) << 3;
#pragma unroll
    for (int kb = 0; kb < 16; ++kb) {
      const float* wp = w_hh + (size_t)grow * 512 + kb * 32 + kofs;
      short8 v;
#pragma unroll
      for (int e = 0; e < 8; ++e) {
        float w = wp[e];
        float hi = bf2f(f2bf(w));
        v[e] = (short)f2bf(w - hi);
      }
      wlo[kb] = v;
    }
  }
  __syncthreads();

  const int arow = mt * 16 + (lane & 15);  // sequence index for A frag
  const int acol = (lane >> 4) << 3;

  for (int t = 0; t < T_STEPS; ++t) {
    if (wave < 6) {
      f32x4 acc = (f32x4){0.f, 0.f, 0.f, 0.f};
      if (t > 0) {
        const u16* ab = hs + ((size_t)(arow * T_STEPS + (t - 1)) << 9) + acol;
#pragma unroll
        for (int kb = 0; kb < 16; ++kb) {
          short8 af = *(const short8*)(ab + kb * 32);
          short8 wh = *(const short8*)(whi + ((ng * 16 + kb) * 64 + lane) * 8);
          acc = __builtin_amdgcn_mfma_f32_16x16x32_bf16(af, wh, acc, 0, 0, 0);
          acc = __builtin_amdgcn_mfma_f32_16x16x32_bf16(af, wlo[kb], acc, 0, 0, 0);
        }
      }
#pragma unroll
      for (int r = 0; r < 4; ++r)
        whb[(mt * 16 + ((lane >> 4) << 2) + r) * 48 + ng * 16 + (lane & 15)] = acc[r];
    } else {
      const int lt = tid - 384;
#pragma unroll
      for (int u = 0; u < 12; ++u) {
        int i = lt + u * 128;
        int seq = i / 48, c = i - seq * 48;
        int g = (c >> 4) * 512 + j0 + (c & 15);
        wxb[i] = bf2f(wx[(size_t)(seq * T_STEPS + t) * 1536 + g]);
      }
    }
    __syncthreads();

    // gates: one (seq, j) per thread
    {
      const int seq = tid >> 4, jj = tid & 15;
      const float* wh = whb + seq * 48;
      const float* wxr = wxb + seq * 48;
      float pr = wxr[jj] + wh[jj] + bsl[jj];
      float pz = wxr[16 + jj] + wh[16 + jj] + bsl[16 + jj];
      float wn_ = wh[32 + jj] + bsl[32 + jj];
      float r = 1.f / (1.f + __expf(-pr));
      float z = 1.f / (1.f + __expf(-pz));
      float nn = tanhf(wxr[32 + jj] + r * wn_);
      float hv = (1.f - z) * nn + z * hold[tid];
      hold[tid] = hv;
      hs[((size_t)(seq * T_STEPS + t) << 9) + j0 + jj] = f2bf(hv);
    }
    __syncthreads();

    // device-scope barrier: per-WG monotonic step flags
    if (tid == 0)
      __hip_atomic_store(&flags[wg], (unsigned)(t + 1), __ATOMIC_RELEASE,
                         __HIP_MEMORY_SCOPE_AGENT);
    if (tid < 32) {
      while (__hip_atomic_load(&flags[tid], __ATOMIC_RELAXED,
                               __HIP_MEMORY_SCOPE_AGENT) < (unsigned)(t + 1)) {
      }
    }
    if (tid == 0) __threadfence();  // acquire: invalidate L1/L2 before next h read
    __syncthreads();
  }
}

// ---------------------------------------------------------------------------
extern "C" void kernel_launch(void* const* d_in, const int* in_sizes, int n_in,
                              void* d_out, int out_size, void* d_ws, size_t ws_size,
                              hipStream_t stream) {
  const float* src = (const float*)d_in[0];   // [32,1024,256]
  const float* w_ih = (const float*)d_in[1];  // [1536,256]
  const float* w_hh = (const float*)d_in[2];  // [1536,512]
  const float* b_ih = (const float*)d_in[3];  // [1536]
  const float* b_hh = (const float*)d_in[4];  // [1536]
  const float* regw = (const float*)d_in[5];  // [256,512]
  const float* regb = (const float*)d_in[6];  // [256]

  char* ws = (char*)d_ws;
  u16* wx = (u16*)(ws);                          // 32768x1536 bf16 = 100663296 B
  u16* hs = (u16*)(ws + 100663296LL);            // 32768x512 bf16 = 33554432 B
  u16* wihb = (u16*)(ws + 134217728LL);          // 1536x256 bf16
  u16* rwb = (u16*)(ws + 135004160LL);           // 256x512 bf16
  unsigned* flags = (unsigned*)(ws + 135266304LL);

  hipMemsetAsync(flags, 0, 256, stream);
  cvt_kernel<<<384, 256, 0, stream>>>(w_ih, wihb, 393216);
  cvt_kernel<<<128, 256, 0, stream>>>(regw, rwb, 131072);

  {  // wx = src @ w_ih^T + b_ih   (bf16 out)
    dim3 g(256, 12);
    gemm_kernel<true, false><<<g, 512, 0, stream>>>((const void*)src, wihb, b_ih,
                                                    (void*)wx, 32768, 1536, 256);
  }
  gru_kernel<<<32, 512, 0, stream>>>(w_hh, b_hh, wx, hs, flags);
  {  // out = hs @ reg_w^T + reg_b  (f32 out)
    dim3 g(256, 2);
    gemm_kernel<false, true><<<g, 512, 0, stream>>>((const void*)hs, rwb, regb,
                                                    d_out, 32768, 256, 512);
  }
}